// Round 6
// baseline (79.546 us; speedup 1.0000x reference)
//
#include <hip/hip_runtime.h>
#include <hip/hip_bf16.h>

#define D_MODEL 1024
#define HEAD 64
#define TSEQ 2048
#define NB 4
#define BT (NB * TSEQ)

typedef __bf16 bf16x8 __attribute__((ext_vector_type(8)));
typedef __bf16 bf16x4 __attribute__((ext_vector_type(4)));
typedef float f32x4 __attribute__((ext_vector_type(4)));

// ---------------------------------------------------------------------------
// Kernel 0: W transpose + bf16 convert. wt[(tsel*64+col)*1024 + k] = W[k][col]
// ---------------------------------------------------------------------------
__global__ __launch_bounds__(256) void wt_kernel(
    const float* __restrict__ Wq, const float* __restrict__ Wk,
    const float* __restrict__ Wv, __bf16* __restrict__ wt)
{
    __shared__ float tile[64][65];
    int tsel = blockIdx.x >> 4;
    int k0 = (blockIdx.x & 15) * 64;
    const float* W = tsel == 0 ? Wq : (tsel == 1 ? Wk : Wv);
    int tid = threadIdx.x;
#pragma unroll
    for (int i = 0; i < 16; ++i) {
        int idx = i * 256 + tid;
        int k = idx >> 6, c = idx & 63;
        tile[k][c] = W[(size_t)(k0 + k) * 64 + c];
    }
    __syncthreads();
#pragma unroll
    for (int i = 0; i < 16; ++i) {
        int idx = i * 256 + tid;
        int c = idx >> 6, k = idx & 63;
        wt[(size_t)(tsel * 64 + c) * 1024 + k0 + k] = (__bf16)tile[k][c];
    }
}

// ---------------------------------------------------------------------------
// Kernel 1: QKV projection as MFMA GEMM, column-partitioned (no LDS).
// Block = 16-row strip, 4 waves. Wave w owns col-tiles jt = w*3..w*3+2
// (48 of 192 cols), FULL K=1024. All waves read the same x rows -> L1 hits.
// acc = 3 f32x4 = 12 VGPRs; no barrier, no LDS reduce.
// MFMA 16x16x32: A: lane(g,c16) holds A[c16][g*8+i]; B: B[g*8+i][c16];
// D: D[g*4+r][c16].
// ---------------------------------------------------------------------------
__global__ __launch_bounds__(256) void qkv_gemm(
    const float* __restrict__ x, const __bf16* __restrict__ wt,
    const float* __restrict__ bq, const float* __restrict__ bk, const float* __restrict__ bv,
    __bf16* __restrict__ qs, __bf16* __restrict__ ks, __bf16* __restrict__ vT)
{
    int r0 = blockIdx.x * 16;
    int tid = threadIdx.x;
    int w = tid >> 6;
    int lane = tid & 63;
    int c16 = lane & 15, g = lane >> 4;

    f32x4 acc[3];
#pragma unroll
    for (int j = 0; j < 3; ++j) acc[j] = (f32x4){0.f, 0.f, 0.f, 0.f};

    const float* xbase = x + (size_t)(r0 + c16) * D_MODEL + g * 8;
    const __bf16* wbase = wt + (size_t)(w * 48 + c16) * D_MODEL + g * 8;

#pragma unroll 4
    for (int kt = 0; kt < 32; ++kt) {
        int k0 = kt * 32;
        float4 xa = *(const float4*)(xbase + k0);
        float4 xb = *(const float4*)(xbase + k0 + 4);
        bf16x8 af;
        af[0] = (__bf16)xa.x; af[1] = (__bf16)xa.y;
        af[2] = (__bf16)xa.z; af[3] = (__bf16)xa.w;
        af[4] = (__bf16)xb.x; af[5] = (__bf16)xb.y;
        af[6] = (__bf16)xb.z; af[7] = (__bf16)xb.w;

#pragma unroll
        for (int j = 0; j < 3; ++j) {
            bf16x8 bfr = *(const bf16x8*)(wbase + (size_t)j * 16 * D_MODEL + k0);
            acc[j] = __builtin_amdgcn_mfma_f32_16x16x32_bf16(af, bfr, acc[j], 0, 0, 0);
        }
    }

#pragma unroll
    for (int j = 0; j < 3; ++j) {
        int jt = w * 3 + j;               // 0..11
        f32x4 s = acc[j];
        int tsel = jt >> 2;               // 0=q 1=k 2=v
        int cm = (jt & 3) * 16 + c16;     // column within its 64-col matrix
        const float* bias = tsel == 0 ? bq : (tsel == 1 ? bk : bv);
        float bval = bias[cm];
        if (tsel == 0) {
#pragma unroll
            for (int r = 0; r < 4; ++r)
                qs[(size_t)(r0 + g * 4 + r) * HEAD + cm] = (__bf16)((s[r] + bval) * 0.03125f);
        } else if (tsel == 1) {
#pragma unroll
            for (int r = 0; r < 4; ++r)
                ks[(size_t)(r0 + g * 4 + r) * HEAD + cm] = (__bf16)(s[r] + bval);
        } else {
#pragma unroll
            for (int r = 0; r < 4; ++r) {
                int row = r0 + g * 4 + r;
                int b = row >> 11, t = row & (TSEQ - 1);
                vT[(size_t)(b * HEAD + cm) * TSEQ + t] = (__bf16)(s[r] + bval);
            }
        }
    }
}

// ---------------------------------------------------------------------------
// Kernel 2: flash attention, 8-way key-split per q-tile.
// Block = 8 waves (512 thr), one 16-row q-tile. Wave w: k-tiles w, w+8, ...
// (max 8 iterations) with private online (m,l,O) and a private LDS P-buffer.
// One barrier, then waves 0-3 combine the 8 partials (exact f32 algebra).
// ---------------------------------------------------------------------------
__global__ __launch_bounds__(512) void attn_mfma(
    const __bf16* __restrict__ qs, const __bf16* __restrict__ ks,
    const __bf16* __restrict__ vT, float* __restrict__ out)
{
    __shared__ __align__(16) __bf16 plds[8][16 * 40];   // 10 KB
    __shared__ __align__(16) f32x4 ocomb[8][4][64];     // 32 KB
    __shared__ float mcomb[8][16];
    __shared__ float lcomb[8][16];

    int blk = blockIdx.x;
    int b = blk >> 7;
    int qt = 127 - (blk & 127);         // heavy q-tiles first
    int qb = qt * 16;

    int tid = threadIdx.x;
    int w = tid >> 6;                   // 0..7
    int lane = tid & 63;
    int g = lane >> 4;
    int c16 = lane & 15;

    const __bf16* qsb = qs + (size_t)(b * TSEQ + qb) * HEAD;
    const __bf16* kb_ = ks + (size_t)b * TSEQ * HEAD;
    const __bf16* vb_ = vT + (size_t)b * HEAD * TSEQ;

    bf16x8 qf0 = *(const bf16x8*)(qsb + c16 * HEAD + g * 8);
    bf16x8 qf1 = *(const bf16x8*)(qsb + c16 * HEAD + 32 + g * 8);

    f32x4 o0 = {0.f, 0.f, 0.f, 0.f}, o1 = o0, o2 = o0, o3 = o0;
    float m[4], l[4];
#pragma unroll
    for (int j = 0; j < 4; ++j) { m[j] = -3.0e38f; l[j] = 0.f; }

    int nt = (qb + 47) >> 5;            // number of 32-key tiles
    __bf16* pl = plds[w];

    for (int ti = w; ti < nt; ti += 8) {
        int kbase = ti * 32;

        // ---- QK^T ----
        const __bf16* kr0 = kb_ + (size_t)(kbase + c16) * HEAD + g * 8;
        bf16x8 k00 = *(const bf16x8*)(kr0);
        bf16x8 k01 = *(const bf16x8*)(kr0 + 32);
        const __bf16* kr1 = kr0 + 16 * HEAD;
        bf16x8 k10 = *(const bf16x8*)(kr1);
        bf16x8 k11 = *(const bf16x8*)(kr1 + 32);

        f32x4 z = {0.f, 0.f, 0.f, 0.f};
        f32x4 s0 = __builtin_amdgcn_mfma_f32_16x16x32_bf16(qf0, k00, z, 0, 0, 0);
        s0 = __builtin_amdgcn_mfma_f32_16x16x32_bf16(qf1, k01, s0, 0, 0, 0);
        f32x4 s1 = __builtin_amdgcn_mfma_f32_16x16x32_bf16(qf0, k10, z, 0, 0, 0);
        s1 = __builtin_amdgcn_mfma_f32_16x16x32_bf16(qf1, k11, s1, 0, 0, 0);

        // ---- causal mask (diagonal tile only) ----
        if (kbase + 31 > qb) {
#pragma unroll
            for (int j = 0; j < 4; ++j) {
                int qr = qb + 4 * g + j;
                if (kbase + c16 > qr)      s0[j] = -3.0e38f;
                if (kbase + 16 + c16 > qr) s1[j] = -3.0e38f;
            }
        }

        // ---- online softmax (per-wave state) ----
        float al[4], p0[4], p1[4], rs[4];
#pragma unroll
        for (int j = 0; j < 4; ++j) {
            float v = fmaxf(s0[j], s1[j]);
            v = fmaxf(v, __shfl_xor(v, 1, 16));
            v = fmaxf(v, __shfl_xor(v, 2, 16));
            v = fmaxf(v, __shfl_xor(v, 4, 16));
            v = fmaxf(v, __shfl_xor(v, 8, 16));
            float mn = fmaxf(m[j], v);
            al[j] = __expf(m[j] - mn);
            m[j] = mn;
        }
#pragma unroll
        for (int j = 0; j < 4; ++j) {
            p0[j] = __expf(s0[j] - m[j]);
            p1[j] = __expf(s1[j] - m[j]);
            float r = p0[j] + p1[j];
            r += __shfl_xor(r, 1, 16);
            r += __shfl_xor(r, 2, 16);
            r += __shfl_xor(r, 4, 16);
            r += __shfl_xor(r, 8, 16);
            rs[j] = r;
        }
#pragma unroll
        for (int j = 0; j < 4; ++j) {
            l[j] = l[j] * al[j] + rs[j];
            o0[j] *= al[j]; o1[j] *= al[j]; o2[j] *= al[j]; o3[j] *= al[j];
        }

        // ---- P: C-layout -> A-layout via private LDS (no barrier) ----
#pragma unroll
        for (int j = 0; j < 4; ++j) {
            pl[(4 * g + j) * 40 + c16]      = (__bf16)p0[j];
            pl[(4 * g + j) * 40 + c16 + 16] = (__bf16)p1[j];
        }
        bf16x8 pf = *(const bf16x8*)(pl + c16 * 40 + g * 8);

        // ---- PV ----
        const __bf16* vbase = vb_ + kbase + g * 8;
        o0 = __builtin_amdgcn_mfma_f32_16x16x32_bf16(pf, *(const bf16x8*)(vbase + (size_t)(c16) * TSEQ), o0, 0, 0, 0);
        o1 = __builtin_amdgcn_mfma_f32_16x16x32_bf16(pf, *(const bf16x8*)(vbase + (size_t)(c16 + 16) * TSEQ), o1, 0, 0, 0);
        o2 = __builtin_amdgcn_mfma_f32_16x16x32_bf16(pf, *(const bf16x8*)(vbase + (size_t)(c16 + 32) * TSEQ), o2, 0, 0, 0);
        o3 = __builtin_amdgcn_mfma_f32_16x16x32_bf16(pf, *(const bf16x8*)(vbase + (size_t)(c16 + 48) * TSEQ), o3, 0, 0, 0);
    }

    // ---- publish partials ----
    ocomb[w][0][lane] = o0;
    ocomb[w][1][lane] = o1;
    ocomb[w][2][lane] = o2;
    ocomb[w][3][lane] = o3;
    if (c16 == 0) {
#pragma unroll
        for (int j = 0; j < 4; ++j) {
            mcomb[w][4 * g + j] = m[j];
            lcomb[w][4 * g + j] = l[j];
        }
    }
    __syncthreads();

    // ---- combine: waves 0-3, wave w finalizes column-group w ----
    if (w < 4) {
        float M[4];
#pragma unroll
        for (int j = 0; j < 4; ++j) {
            int row = 4 * g + j;
            float mm = mcomb[0][row];
#pragma unroll
            for (int sw = 1; sw < 8; ++sw) mm = fmaxf(mm, mcomb[sw][row]);
            M[j] = mm;
        }
        f32x4 O = {0.f, 0.f, 0.f, 0.f};
        float L[4] = {0.f, 0.f, 0.f, 0.f};
#pragma unroll
        for (int sw = 0; sw < 8; ++sw) {
            f32x4 po = ocomb[sw][w][lane];
#pragma unroll
            for (int j = 0; j < 4; ++j) {
                int row = 4 * g + j;
                float e = __expf(mcomb[sw][row] - M[j]);
                L[j] += lcomb[sw][row] * e;
                O[j] += po[j] * e;
            }
        }
        float* obase = out + (size_t)(b * TSEQ + qb) * HEAD + w * 16 + c16;
#pragma unroll
        for (int j = 0; j < 4; ++j)
            obase[(size_t)(4 * g + j) * HEAD] = O[j] / L[j];
    }
}

extern "C" void kernel_launch(void* const* d_in, const int* in_sizes, int n_in,
                              void* d_out, int out_size, void* d_ws, size_t ws_size,
                              hipStream_t stream) {
    const float* x  = (const float*)d_in[0];
    const float* Wk = (const float*)d_in[1];
    const float* Wq = (const float*)d_in[2];
    const float* Wv = (const float*)d_in[3];
    const float* bk = (const float*)d_in[4];
    const float* bq = (const float*)d_in[5];
    const float* bv = (const float*)d_in[6];
    float* out = (float*)d_out;

    __bf16* qs = (__bf16*)d_ws;                        // [BT][64]        1 MB
    __bf16* ks = qs + (size_t)BT * HEAD;               // [BT][64]        1 MB
    __bf16* vT = ks + (size_t)BT * HEAD;               // [NB][64][TSEQ]  1 MB
    __bf16* wt = vT + (size_t)BT * HEAD;               // [192][1024]     384 KB

    wt_kernel<<<48, 256, 0, stream>>>(Wq, Wk, Wv, wt);
    qkv_gemm<<<BT / 16, 256, 0, stream>>>(x, wt, bq, bk, bv, qs, ks, vT);
    attn_mfma<<<512, 512, 0, stream>>>(qs, ks, vT, out);
}

// Round 7
// 72.100 us; speedup vs baseline: 1.1033x; 1.1033x over previous
//
#include <hip/hip_runtime.h>
#include <hip/hip_bf16.h>

#define D_MODEL 1024
#define HEAD 64
#define TSEQ 2048
#define NB 4
#define BT (NB * TSEQ)

typedef __bf16 bf16x8 __attribute__((ext_vector_type(8)));
typedef __bf16 bf16x4 __attribute__((ext_vector_type(4)));
typedef float f32x4 __attribute__((ext_vector_type(4)));

// ---------------------------------------------------------------------------
// Kernel 0: W transpose + bf16 convert. wt[(tsel*64+col)*1024 + k] = W[k][col]
// ---------------------------------------------------------------------------
__global__ __launch_bounds__(256) void wt_kernel(
    const float* __restrict__ Wq, const float* __restrict__ Wk,
    const float* __restrict__ Wv, __bf16* __restrict__ wt)
{
    __shared__ float tile[64][65];
    int tsel = blockIdx.x >> 4;
    int k0 = (blockIdx.x & 15) * 64;
    const float* W = tsel == 0 ? Wq : (tsel == 1 ? Wk : Wv);
    int tid = threadIdx.x;
#pragma unroll
    for (int i = 0; i < 16; ++i) {
        int idx = i * 256 + tid;
        int k = idx >> 6, c = idx & 63;
        tile[k][c] = W[(size_t)(k0 + k) * 64 + c];
    }
    __syncthreads();
#pragma unroll
    for (int i = 0; i < 16; ++i) {
        int idx = i * 256 + tid;
        int c = idx >> 6, k = idx & 63;
        wt[(size_t)(tsel * 64 + c) * 1024 + k0 + k] = (__bf16)tile[k][c];
    }
}

// ---------------------------------------------------------------------------
// Kernel 1: QKV MFMA GEMM, 8 waves = 4-way K-split x 2-way col-split.
// Block = one 16-row strip, 512 thr. Wave w: kq=w>>1 (K quarter, 256),
// ch=w&1 (96 cols = 6 col-tiles). 8-iteration K loop, 6 accumulators,
// rolling x prefetch. 48 KB LDS cross-wave reduce (4 partials per tile),
// fused bias/scale/bf16 epilogue (q pre-scaled, V transposed).
// MFMA 16x16x32: A: lane(g,c16)=A[c16][g*8+i]; B: B[g*8+i][c16];
// D: D[g*4+r][c16].
// ---------------------------------------------------------------------------
__global__ __launch_bounds__(512) void qkv_gemm(
    const float* __restrict__ x, const __bf16* __restrict__ wt,
    const float* __restrict__ bq, const float* __restrict__ bk, const float* __restrict__ bv,
    __bf16* __restrict__ qs, __bf16* __restrict__ ks, __bf16* __restrict__ vT)
{
    __shared__ f32x4 red[8][6][64];   // 48 KB [wave][coltile][lane]

    int r0 = blockIdx.x * 16;
    int tid = threadIdx.x;
    int w = tid >> 6;                 // 0..7
    int kq = w >> 1;                  // K quarter
    int ch = w & 1;                   // column half (96 cols)
    int lane = tid & 63;
    int c16 = lane & 15, g = lane >> 4;

    f32x4 acc[6];
#pragma unroll
    for (int j = 0; j < 6; ++j) acc[j] = (f32x4){0.f, 0.f, 0.f, 0.f};

    const float* xbase = x + (size_t)(r0 + c16) * D_MODEL + kq * 256 + g * 8;
    const __bf16* wbase = wt + (size_t)(ch * 96 + c16) * D_MODEL + kq * 256 + g * 8;

    float4 xa = *(const float4*)(xbase);
    float4 xb = *(const float4*)(xbase + 4);

#pragma unroll
    for (int kt = 0; kt < 8; ++kt) {
        int k0 = kt * 32;
        float4 xa_n, xb_n;
        if (kt < 7) {                              // rolling prefetch
            xa_n = *(const float4*)(xbase + k0 + 32);
            xb_n = *(const float4*)(xbase + k0 + 36);
        }
        bf16x8 af;
        af[0] = (__bf16)xa.x; af[1] = (__bf16)xa.y;
        af[2] = (__bf16)xa.z; af[3] = (__bf16)xa.w;
        af[4] = (__bf16)xb.x; af[5] = (__bf16)xb.y;
        af[6] = (__bf16)xb.z; af[7] = (__bf16)xb.w;

        const __bf16* wk = wbase + k0;
#pragma unroll
        for (int j = 0; j < 6; ++j) {
            bf16x8 bfr = *(const bf16x8*)(wk + (size_t)j * 16 * D_MODEL);
            acc[j] = __builtin_amdgcn_mfma_f32_16x16x32_bf16(af, bfr, acc[j], 0, 0, 0);
        }
        xa = xa_n; xb = xb_n;
    }

#pragma unroll
    for (int j = 0; j < 6; ++j) red[w][j][lane] = acc[j];
    __syncthreads();

    // 12 global col-tiles; wave w finalizes jt=w, waves 0-3 also jt=8+w.
#pragma unroll
    for (int pass = 0; pass < 2; ++pass) {
        if (pass == 1 && w >= 4) break;
        int jt = (pass == 0) ? w : 8 + w;
        int chh = jt / 6, j = jt % 6;
        f32x4 s = red[0 + chh][j][lane] + red[2 + chh][j][lane]
                + red[4 + chh][j][lane] + red[6 + chh][j][lane];
        int tsel = jt >> 2;               // 0=q 1=k 2=v
        int cm = (jt & 3) * 16 + c16;     // column within its 64-col matrix
        const float* bias = tsel == 0 ? bq : (tsel == 1 ? bk : bv);
        float bval = bias[cm];
        if (tsel == 0) {
#pragma unroll
            for (int r = 0; r < 4; ++r)
                qs[(size_t)(r0 + g * 4 + r) * HEAD + cm] = (__bf16)((s[r] + bval) * 0.03125f);
        } else if (tsel == 1) {
#pragma unroll
            for (int r = 0; r < 4; ++r)
                ks[(size_t)(r0 + g * 4 + r) * HEAD + cm] = (__bf16)(s[r] + bval);
        } else {
#pragma unroll
            for (int r = 0; r < 4; ++r) {
                int row = r0 + g * 4 + r;
                int b = row >> 11, t = row & (TSEQ - 1);
                vT[(size_t)(b * HEAD + cm) * TSEQ + t] = (__bf16)(s[r] + bval);
            }
        }
    }
}

// ---------------------------------------------------------------------------
// Kernel 2: flash attention, 8-way key-split per q-tile (unchanged, round 6).
// ---------------------------------------------------------------------------
__global__ __launch_bounds__(512) void attn_mfma(
    const __bf16* __restrict__ qs, const __bf16* __restrict__ ks,
    const __bf16* __restrict__ vT, float* __restrict__ out)
{
    __shared__ __align__(16) __bf16 plds[8][16 * 40];   // 10 KB
    __shared__ __align__(16) f32x4 ocomb[8][4][64];     // 32 KB
    __shared__ float mcomb[8][16];
    __shared__ float lcomb[8][16];

    int blk = blockIdx.x;
    int b = blk >> 7;
    int qt = 127 - (blk & 127);         // heavy q-tiles first
    int qb = qt * 16;

    int tid = threadIdx.x;
    int w = tid >> 6;                   // 0..7
    int lane = tid & 63;
    int g = lane >> 4;
    int c16 = lane & 15;

    const __bf16* qsb = qs + (size_t)(b * TSEQ + qb) * HEAD;
    const __bf16* kb_ = ks + (size_t)b * TSEQ * HEAD;
    const __bf16* vb_ = vT + (size_t)b * HEAD * TSEQ;

    bf16x8 qf0 = *(const bf16x8*)(qsb + c16 * HEAD + g * 8);
    bf16x8 qf1 = *(const bf16x8*)(qsb + c16 * HEAD + 32 + g * 8);

    f32x4 o0 = {0.f, 0.f, 0.f, 0.f}, o1 = o0, o2 = o0, o3 = o0;
    float m[4], l[4];
#pragma unroll
    for (int j = 0; j < 4; ++j) { m[j] = -3.0e38f; l[j] = 0.f; }

    int nt = (qb + 47) >> 5;
    __bf16* pl = plds[w];

    for (int ti = w; ti < nt; ti += 8) {
        int kbase = ti * 32;

        const __bf16* kr0 = kb_ + (size_t)(kbase + c16) * HEAD + g * 8;
        bf16x8 k00 = *(const bf16x8*)(kr0);
        bf16x8 k01 = *(const bf16x8*)(kr0 + 32);
        const __bf16* kr1 = kr0 + 16 * HEAD;
        bf16x8 k10 = *(const bf16x8*)(kr1);
        bf16x8 k11 = *(const bf16x8*)(kr1 + 32);

        f32x4 z = {0.f, 0.f, 0.f, 0.f};
        f32x4 s0 = __builtin_amdgcn_mfma_f32_16x16x32_bf16(qf0, k00, z, 0, 0, 0);
        s0 = __builtin_amdgcn_mfma_f32_16x16x32_bf16(qf1, k01, s0, 0, 0, 0);
        f32x4 s1 = __builtin_amdgcn_mfma_f32_16x16x32_bf16(qf0, k10, z, 0, 0, 0);
        s1 = __builtin_amdgcn_mfma_f32_16x16x32_bf16(qf1, k11, s1, 0, 0, 0);

        if (kbase + 31 > qb) {
#pragma unroll
            for (int j = 0; j < 4; ++j) {
                int qr = qb + 4 * g + j;
                if (kbase + c16 > qr)      s0[j] = -3.0e38f;
                if (kbase + 16 + c16 > qr) s1[j] = -3.0e38f;
            }
        }

        float al[4], p0[4], p1[4], rs[4];
#pragma unroll
        for (int j = 0; j < 4; ++j) {
            float v = fmaxf(s0[j], s1[j]);
            v = fmaxf(v, __shfl_xor(v, 1, 16));
            v = fmaxf(v, __shfl_xor(v, 2, 16));
            v = fmaxf(v, __shfl_xor(v, 4, 16));
            v = fmaxf(v, __shfl_xor(v, 8, 16));
            float mn = fmaxf(m[j], v);
            al[j] = __expf(m[j] - mn);
            m[j] = mn;
        }
#pragma unroll
        for (int j = 0; j < 4; ++j) {
            p0[j] = __expf(s0[j] - m[j]);
            p1[j] = __expf(s1[j] - m[j]);
            float r = p0[j] + p1[j];
            r += __shfl_xor(r, 1, 16);
            r += __shfl_xor(r, 2, 16);
            r += __shfl_xor(r, 4, 16);
            r += __shfl_xor(r, 8, 16);
            rs[j] = r;
        }
#pragma unroll
        for (int j = 0; j < 4; ++j) {
            l[j] = l[j] * al[j] + rs[j];
            o0[j] *= al[j]; o1[j] *= al[j]; o2[j] *= al[j]; o3[j] *= al[j];
        }

#pragma unroll
        for (int j = 0; j < 4; ++j) {
            pl[(4 * g + j) * 40 + c16]      = (__bf16)p0[j];
            pl[(4 * g + j) * 40 + c16 + 16] = (__bf16)p1[j];
        }
        bf16x8 pf = *(const bf16x8*)(pl + c16 * 40 + g * 8);

        const __bf16* vbase = vb_ + kbase + g * 8;
        o0 = __builtin_amdgcn_mfma_f32_16x16x32_bf16(pf, *(const bf16x8*)(vbase + (size_t)(c16) * TSEQ), o0, 0, 0, 0);
        o1 = __builtin_amdgcn_mfma_f32_16x16x32_bf16(pf, *(const bf16x8*)(vbase + (size_t)(c16 + 16) * TSEQ), o1, 0, 0, 0);
        o2 = __builtin_amdgcn_mfma_f32_16x16x32_bf16(pf, *(const bf16x8*)(vbase + (size_t)(c16 + 32) * TSEQ), o2, 0, 0, 0);
        o3 = __builtin_amdgcn_mfma_f32_16x16x32_bf16(pf, *(const bf16x8*)(vbase + (size_t)(c16 + 48) * TSEQ), o3, 0, 0, 0);
    }

    ocomb[w][0][lane] = o0;
    ocomb[w][1][lane] = o1;
    ocomb[w][2][lane] = o2;
    ocomb[w][3][lane] = o3;
    if (c16 == 0) {
#pragma unroll
        for (int j = 0; j < 4; ++j) {
            mcomb[w][4 * g + j] = m[j];
            lcomb[w][4 * g + j] = l[j];
        }
    }
    __syncthreads();

    if (w < 4) {
        float M[4];
#pragma unroll
        for (int j = 0; j < 4; ++j) {
            int row = 4 * g + j;
            float mm = mcomb[0][row];
#pragma unroll
            for (int sw = 1; sw < 8; ++sw) mm = fmaxf(mm, mcomb[sw][row]);
            M[j] = mm;
        }
        f32x4 O = {0.f, 0.f, 0.f, 0.f};
        float L[4] = {0.f, 0.f, 0.f, 0.f};
#pragma unroll
        for (int sw = 0; sw < 8; ++sw) {
            f32x4 po = ocomb[sw][w][lane];
#pragma unroll
            for (int j = 0; j < 4; ++j) {
                int row = 4 * g + j;
                float e = __expf(mcomb[sw][row] - M[j]);
                L[j] += lcomb[sw][row] * e;
                O[j] += po[j] * e;
            }
        }
        float* obase = out + (size_t)(b * TSEQ + qb) * HEAD + w * 16 + c16;
#pragma unroll
        for (int j = 0; j < 4; ++j)
            obase[(size_t)(4 * g + j) * HEAD] = O[j] / L[j];
    }
}

extern "C" void kernel_launch(void* const* d_in, const int* in_sizes, int n_in,
                              void* d_out, int out_size, void* d_ws, size_t ws_size,
                              hipStream_t stream) {
    const float* x  = (const float*)d_in[0];
    const float* Wk = (const float*)d_in[1];
    const float* Wq = (const float*)d_in[2];
    const float* Wv = (const float*)d_in[3];
    const float* bk = (const float*)d_in[4];
    const float* bq = (const float*)d_in[5];
    const float* bv = (const float*)d_in[6];
    float* out = (float*)d_out;

    __bf16* qs = (__bf16*)d_ws;                        // [BT][64]        1 MB
    __bf16* ks = qs + (size_t)BT * HEAD;               // [BT][64]        1 MB
    __bf16* vT = ks + (size_t)BT * HEAD;               // [NB][64][TSEQ]  1 MB
    __bf16* wt = vT + (size_t)BT * HEAD;               // [192][1024]     384 KB

    wt_kernel<<<48, 256, 0, stream>>>(Wq, Wk, Wv, wt);
    qkv_gemm<<<BT / 16, 512, 0, stream>>>(x, wt, bq, bk, bv, qs, ks, vT);
    attn_mfma<<<512, 512, 0, stream>>>(qs, ks, vT, out);
}